// Round 4
// baseline (221.853 us; speedup 1.0000x reference)
//
#include <hip/hip_runtime.h>
#include <hip/hip_bf16.h>
#include <stdint.h>

#define OUTN   8192
#define INN    8192
#define NGRP   64
#define BATCHN 64
#define KSPLIT 8
#define KCHUNK (INN / KSPLIT)   /* 1024 */
#define NITER  (KCHUNK / 128)   /* 8 groups of 128 per chunk */
#define OSZ    (BATCHN * OUTN)  /* 524288 floats = 2 MB */

typedef __attribute__((ext_vector_type(8))) short bf16x8;
typedef __attribute__((ext_vector_type(4))) float f32x4;
typedef __attribute__((ext_vector_type(4))) unsigned int u32x4;

__device__ __forceinline__ unsigned short f2bf(float f) {
  __hip_bfloat16 h = __float2bfloat16(f);
  return __builtin_bit_cast(unsigned short, h);
}
__device__ __forceinline__ float bf2f(unsigned short h) {
  unsigned int u = ((unsigned int)h) << 16;
  return __builtin_bit_cast(float, u);
}

// xsum[g][b] = sum over k in group g of bf16-rounded x[b][k]  (64x64 fp32)
__global__ void qlin_prep(const float* __restrict__ x, float* __restrict__ xsum) {
  const int b = blockIdx.x;
  const int t = threadIdx.x;
  const float* xrow = x + (size_t)b * INN + t * 32;
  float s = 0.0f;
#pragma unroll
  for (int i = 0; i < 8; ++i) {
    float4 v = *(const float4*)(xrow + i * 4);
    s += bf2f(f2bf(v.x)) + bf2f(f2bf(v.y)) + bf2f(f2bf(v.z)) + bf2f(f2bf(v.w));
  }
  __shared__ float part[256];
  part[t] = s;
  __syncthreads();
  if (t < NGRP) {
    float g = part[4 * t] + part[4 * t + 1] + part[4 * t + 2] + part[4 * t + 3];
    xsum[t * BATCHN + b] = g;
  }
}

// xswz[kb][b][j] = bf16(x[b][kb*8+j]) — A-fragment-major, 1 MB, L2-resident.
__global__ void qlin_swz(const float* __restrict__ x, unsigned short* __restrict__ xswz) {
  const int idx = blockIdx.x * 256 + threadIdx.x;  // 0..65535
  const int b  = idx & 63;
  const int kb = idx >> 6;
  const float* p = x + (size_t)b * INN + kb * 8;
  float4 v0 = *(const float4*)p;
  float4 v1 = *(const float4*)(p + 4);
  u32x4 o;
  o.x = (unsigned)f2bf(v0.x) | ((unsigned)f2bf(v0.y) << 16);
  o.y = (unsigned)f2bf(v0.z) | ((unsigned)f2bf(v0.w) << 16);
  o.z = (unsigned)f2bf(v1.x) | ((unsigned)f2bf(v1.y) << 16);
  o.w = (unsigned)f2bf(v1.z) | ((unsigned)f2bf(v1.w) << 16);
  *(u32x4*)&xswz[(size_t)idx * 8] = o;
}

__device__ __forceinline__ bf16x8 dequant8(int4 c) {
  // byte v -> bf16 pair (128+lo | 128+hi) = 0x4300|nibble, exact in bf16
  u32x4 bw;
  bw.x = 0x43004300u | ((unsigned)c.x & 0xFu) | (((unsigned)c.x & 0xF0u) << 12);
  bw.y = 0x43004300u | ((unsigned)c.y & 0xFu) | (((unsigned)c.y & 0xF0u) << 12);
  bw.z = 0x43004300u | ((unsigned)c.z & 0xFu) | (((unsigned)c.z & 0xF0u) << 12);
  bw.w = 0x43004300u | ((unsigned)c.w & 0xFu) | (((unsigned)c.w & 0xF0u) << 12);
  return __builtin_bit_cast(bf16x8, bw);
}

__global__ __launch_bounds__(256, 2) void qlin_main(
    const int* __restrict__ packed, const float* __restrict__ scales,
    const unsigned short* __restrict__ xswz, const float* __restrict__ xsum,
    float* __restrict__ out, float* __restrict__ part) {
  const int bx    = blockIdx.x;
  const int ks    = bx & (KSPLIT - 1);
  const int ntile = bx >> 3;
  const int o0    = ntile * 64;
  const int g0    = ks * NITER;

  const int t    = threadIdx.x;
  const int lane = t & 63;
  const int w    = t >> 6;
  const int r    = lane & 15;
  const int q    = lane >> 4;
  const int orow = o0 + w * 16 + r;

  // xsum staged to LDS once; fold reads go through lgkmcnt (vmcnt stays clean)
  __shared__ float xs[NITER][BATCHN];  // 2 KB
#pragma unroll
  for (int i = 0; i < 2; ++i) {
    int v = t * 2 + i;
    xs[v >> 6][v & 63] = xsum[(g0 + (v >> 6)) * BATCHN + (v & 63)];
  }
  __syncthreads();  // only barrier in the kernel (before any heavy loads)

  float4 sa = *(const float4*)&scales[(size_t)orow * NGRP + g0];
  float4 sb = *(const float4*)&scales[(size_t)orow * NGRP + g0 + 4];
  float sreg[8] = {sa.x, sa.y, sa.z, sa.w, sb.x, sb.y, sb.z, sb.w};

  // B: lane (q,r) reads row orow; group g, slice s -> int4 at g*64 + s*16
  const int* bptr = packed + (size_t)orow * (INN / 2) + ks * (KCHUNK / 2) + q * 4;
  // A: fragment-major bf16; frag (g,s,mt) at ((g*16+s*4)*64 + mt*16)*8 shorts
  const unsigned short* aptr = xswz + ((size_t)(ks * 128 + q) * 64 + r) * 8;

  int4  bv[3][4];   // 3-group rolling buffer (HBM stream, ~2 groups in flight)
  u32x4 av[2][16];  // 2-group double buffer (L2 stream)

  auto loadB = [&](int g, int4* dst) {
#pragma unroll
    for (int s = 0; s < 4; ++s)
      dst[s] = *(const int4*)(bptr + g * 64 + s * 16);
  };
  auto loadA = [&](int g, u32x4* dst) {
#pragma unroll
    for (int s = 0; s < 4; ++s)
#pragma unroll
      for (int mt = 0; mt < 4; ++mt)
        dst[s * 4 + mt] = *(const u32x4*)(aptr + ((size_t)(g * 16 + s * 4) * 64 + mt * 16) * 8);
  };

  loadB(0, bv[0]); loadB(1, bv[1]);
  loadA(0, av[0]); loadA(1, av[1]);

  f32x4 facc[4];
#pragma unroll
  for (int mt = 0; mt < 4; ++mt) facc[mt] = (f32x4){0.f, 0.f, 0.f, 0.f};

#pragma unroll
  for (int g = 0; g < NITER; ++g) {
    if (g + 2 < NITER) loadB(g + 2, bv[(g + 2) % 3]);  // oldest-first in vmcnt FIFO

    f32x4 gacc[4];
#pragma unroll
    for (int mt = 0; mt < 4; ++mt) gacc[mt] = (f32x4){0.f, 0.f, 0.f, 0.f};

#pragma unroll
    for (int s = 0; s < 4; ++s) {
      bf16x8 bfv = dequant8(bv[g % 3][s]);
#pragma unroll
      for (int mt = 0; mt < 4; ++mt)
        gacc[mt] = __builtin_amdgcn_mfma_f32_16x16x32_bf16(
            __builtin_bit_cast(bf16x8, av[g & 1][s * 4 + mt]), bfv, gacc[mt], 0, 0, 0);
    }

    // A(g) fully consumed above -> refill same slots for g+2
    if (g + 2 < NITER) loadA(g + 2, av[g & 1]);

    // fold group g: y += s[o,g] * (S_g - 136 * xsum_g[b])
    float sg = sreg[g];
#pragma unroll
    for (int mt = 0; mt < 4; ++mt) {
      f32x4 xv = *(const f32x4*)&xs[g][mt * 16 + q * 4];
#pragma unroll
      for (int rr = 0; rr < 4; ++rr)
        facc[mt][rr] += sg * (gacc[mt][rr] - 136.0f * xv[rr]);
    }
  }

  if (part) {
    float* pb = part + (size_t)ks * OSZ;
#pragma unroll
    for (int mt = 0; mt < 4; ++mt)
#pragma unroll
      for (int rr = 0; rr < 4; ++rr) {
        int m = mt * 16 + q * 4 + rr;
        pb[(size_t)m * OUTN + orow] = facc[mt][rr];
      }
  } else {
#pragma unroll
    for (int mt = 0; mt < 4; ++mt)
#pragma unroll
      for (int rr = 0; rr < 4; ++rr) {
        int m = mt * 16 + q * 4 + rr;
        atomicAdd(&out[(size_t)m * OUTN + orow], facc[mt][rr]);
      }
  }
}

__global__ void qlin_reduce(const float* __restrict__ part, float* __restrict__ out) {
  const size_t i = ((size_t)blockIdx.x * 256 + threadIdx.x) * 4;
  float4 s = *(const float4*)(part + i);
#pragma unroll
  for (int ks = 1; ks < KSPLIT; ++ks) {
    float4 v = *(const float4*)(part + (size_t)ks * OSZ + i);
    s.x += v.x; s.y += v.y; s.z += v.z; s.w += v.w;
  }
  *(float4*)(out + i) = s;
}

extern "C" void kernel_launch(void* const* d_in, const int* in_sizes, int n_in,
                              void* d_out, int out_size, void* d_ws, size_t ws_size,
                              hipStream_t stream) {
  const float* x      = (const float*)d_in[0];
  const int*   packed = (const int*)d_in[1];
  const float* scales = (const float*)d_in[2];
  float* out = (float*)d_out;

  char* ws = (char*)d_ws;
  float*          xsum = (float*)ws;                     // 16 KB
  unsigned short* xswz = (unsigned short*)(ws + 16384);  // 1 MB
  const size_t part_need = 16384 + 1048576 + (size_t)KSPLIT * OSZ * sizeof(float);
  float* part = (ws_size >= part_need) ? (float*)(ws + 16384 + 1048576) : nullptr;

  qlin_prep<<<BATCHN, 256, 0, stream>>>(x, xsum);
  qlin_swz<<<(INN / 8) * BATCHN / 256, 256, 0, stream>>>(x, xswz);
  if (!part)
    hipMemsetAsync(d_out, 0, (size_t)out_size * sizeof(float), stream);
  qlin_main<<<(OUTN / 64) * KSPLIT, 256, 0, stream>>>(packed, scales, xswz, xsum, out, part);
  if (part)
    qlin_reduce<<<OSZ / 4 / 256, 256, 0, stream>>>(part, out);
}

// Round 5
// 209.292 us; speedup vs baseline: 1.0600x; 1.0600x over previous
//
#include <hip/hip_runtime.h>
#include <hip/hip_bf16.h>
#include <stdint.h>

#define OUTN   8192
#define INN    8192
#define NGRP   64
#define BATCHN 64
#define BN     64
#define BK     128
#define KSPLIT 8
#define KCHUNK (INN / KSPLIT)   /* 1024 */
#define NITER  (KCHUNK / BK)    /* 8 */
#define OSZ    (BATCHN * OUTN)  /* 524288 floats = 2 MB */

typedef __attribute__((ext_vector_type(8))) short bf16x8;
typedef __attribute__((ext_vector_type(4))) float f32x4;
typedef __attribute__((ext_vector_type(4))) unsigned int u32x4;

// barrier that does NOT drain vmcnt: global prefetch stays in flight (m139)
#define BARRIER_KEEP_VMEM() asm volatile("s_waitcnt lgkmcnt(0)\n\ts_barrier" ::: "memory")

__device__ __forceinline__ unsigned short f2bf(float f) {
  __hip_bfloat16 h = __float2bfloat16(f);
  return __builtin_bit_cast(unsigned short, h);
}
__device__ __forceinline__ float bf2f(unsigned short h) {
  unsigned int u = ((unsigned int)h) << 16;
  return __builtin_bit_cast(float, u);
}

// xsum[g][b] = sum over k in group g of bf16-rounded x[b][k]  (64x64 fp32)
__global__ void qlin_prep(const float* __restrict__ x, float* __restrict__ xsum) {
  const int b = blockIdx.x;
  const int t = threadIdx.x;
  const float* xrow = x + (size_t)b * INN + t * 32;
  float s = 0.0f;
#pragma unroll
  for (int i = 0; i < 8; ++i) {
    float4 v = *(const float4*)(xrow + i * 4);
    s += bf2f(f2bf(v.x)) + bf2f(f2bf(v.y)) + bf2f(f2bf(v.z)) + bf2f(f2bf(v.w));
  }
  __shared__ float part[256];
  part[t] = s;
  __syncthreads();
  if (t < NGRP) {
    float g = part[4 * t] + part[4 * t + 1] + part[4 * t + 2] + part[4 * t + 3];
    xsum[t * BATCHN + b] = g;
  }
}

// xswz[b][k] = bf16(x[b][k]), plain row-major, 1 MB (L2/L3-resident)
__global__ void qlin_swz(const float* __restrict__ x, unsigned short* __restrict__ xswz) {
  const int idx = blockIdx.x * 256 + threadIdx.x;  // 0..65535
  const int b  = idx >> 10;
  const int kc = idx & 1023;
  const float* p = x + (size_t)b * INN + kc * 8;
  float4 v0 = *(const float4*)p;
  float4 v1 = *(const float4*)(p + 4);
  u32x4 o;
  o.x = (unsigned)f2bf(v0.x) | ((unsigned)f2bf(v0.y) << 16);
  o.y = (unsigned)f2bf(v0.z) | ((unsigned)f2bf(v0.w) << 16);
  o.z = (unsigned)f2bf(v1.x) | ((unsigned)f2bf(v1.y) << 16);
  o.w = (unsigned)f2bf(v1.z) | ((unsigned)f2bf(v1.w) << 16);
  *(u32x4*)&xswz[(size_t)b * INN + kc * 8] = o;
}

#define PKS 17    /* pk_c row stride, dwords: 16 data + 1 pad */
#define XTS 136   /* xt row stride, ushorts: 128 data + 8 pad (272 B, 16B-aligned) */

__global__ __launch_bounds__(256, 4) void qlin_main(
    const int* __restrict__ packed, const float* __restrict__ scales,
    const unsigned short* __restrict__ xswz, const float* __restrict__ xsum,
    float* __restrict__ out, float* __restrict__ part) {
  const int bx    = blockIdx.x;
  const int ks    = bx & (KSPLIT - 1);
  const int ntile = bx >> 3;
  const int o0    = ntile * BN;
  const int g0    = ks * NITER;

  const int t    = threadIdx.x;
  const int lane = t & 63;
  const int w    = t >> 6;
  const int r    = lane & 15;
  const int q    = lane >> 4;
  const int orow = o0 + w * 16 + r;

  __shared__ __align__(16) unsigned int   pk_c[BN * PKS];    // 4.3 KB
  __shared__ __align__(16) unsigned short xt[BATCHN * XTS];  // 17.4 KB
  __shared__ __align__(16) float          xs[NITER][BATCHN]; // 2 KB

  // stage xsum once
#pragma unroll
  for (int i = 0; i < 2; ++i) {
    int v = t * 2 + i;
    xs[v >> 6][v & 63] = xsum[(g0 + (v >> 6)) * BATCHN + (v & 63)];
  }

  // per-lane scales for its row
  float4 sa = *(const float4*)&scales[(size_t)orow * NGRP + g0];
  float4 sb = *(const float4*)&scales[(size_t)orow * NGRP + g0 + 4];
  float sreg[8] = {sa.x, sa.y, sa.z, sa.w, sb.x, sb.y, sb.z, sb.w};

  int4  pkr[4];
  u32x4 xr4[4];
  const int prow = t >> 4, pcol = t & 15;  // packed: 16 lanes x 16B = 256B/row
  const int xrow = t >> 2, xseg = t & 3;   // x: 4 lanes x 64B = 256B(bf16)/row

  auto load_tile = [&](int i) {
    const int kk2 = ks * (KCHUNK / 2) + i * (BK / 2);
    const int* pbase = packed + (size_t)(o0 + prow) * (INN / 2) + kk2 + pcol * 4;
#pragma unroll
    for (int j = 0; j < 4; ++j)
      pkr[j] = *(const int4*)(pbase + (size_t)(16 * j) * (INN / 2));
    const unsigned short* xbase =
        xswz + (size_t)xrow * INN + ks * KCHUNK + i * BK + xseg * 32;
#pragma unroll
    for (int j = 0; j < 4; ++j)
      xr4[j] = *(const u32x4*)(xbase + j * 8);
  };

  auto store_tile = [&]() {
#pragma unroll
    for (int j = 0; j < 4; ++j) {
      unsigned int c = (unsigned)pkr[j].x | ((unsigned)pkr[j].y << 8) |
                       ((unsigned)pkr[j].z << 16) | ((unsigned)pkr[j].w << 24);
      pk_c[(prow + 16 * j) * PKS + pcol] = c;
    }
#pragma unroll
    for (int j = 0; j < 4; ++j)
      *(u32x4*)&xt[xrow * XTS + xseg * 32 + j * 8] = xr4[j];
  };

  f32x4 facc[4];
#pragma unroll
  for (int mt = 0; mt < 4; ++mt) facc[mt] = (f32x4){0.f, 0.f, 0.f, 0.f};

  load_tile(0);

  for (int i = 0; i < NITER; ++i) {
    BARRIER_KEEP_VMEM();   // prev-iter LDS reads done; vmcnt untouched
    store_tile();          // compiler waits on pkr/xr4 only
    if (i + 1 < NITER) load_tile(i + 1);  // stays in flight through compute
    BARRIER_KEEP_VMEM();   // tile visible; prefetch still in flight

    f32x4 gacc[4];
#pragma unroll
    for (int mt = 0; mt < 4; ++mt) gacc[mt] = (f32x4){0.f, 0.f, 0.f, 0.f};

#pragma unroll
    for (int kq = 0; kq < 4; ++kq) {
      bf16x8 af[4];
#pragma unroll
      for (int mt = 0; mt < 4; ++mt)
        af[mt] = *(const bf16x8*)&xt[(mt * 16 + r) * XTS + kq * 32 + q * 8];

      unsigned int c = pk_c[(w * 16 + r) * PKS + kq * 4 + q];
      u32x4 bw;
      bw.x = 0x43004300u | (c & 0xFu) | ((c & 0xF0u) << 12);
      bw.y = 0x43004300u | ((c >> 8) & 0xFu) | (((c >> 8) & 0xF0u) << 12);
      bw.z = 0x43004300u | ((c >> 16) & 0xFu) | (((c >> 16) & 0xF0u) << 12);
      bw.w = 0x43004300u | ((c >> 24) & 0xFu) | (((c >> 24) & 0xF0u) << 12);
      bf16x8 bfv = __builtin_bit_cast(bf16x8, bw);

#pragma unroll
      for (int mt = 0; mt < 4; ++mt)
        gacc[mt] = __builtin_amdgcn_mfma_f32_16x16x32_bf16(af[mt], bfv, gacc[mt], 0, 0, 0);
    }

    // fold group i: y += s[o,g] * (S_g - 136 * xsum_g[b])
    float sg = sreg[i];
#pragma unroll
    for (int mt = 0; mt < 4; ++mt) {
      f32x4 xv = *(const f32x4*)&xs[i][mt * 16 + q * 4];
#pragma unroll
      for (int rr = 0; rr < 4; ++rr)
        facc[mt][rr] += sg * (gacc[mt][rr] - 136.0f * xv[rr]);
    }
  }

  if (part) {
    float* pb = part + (size_t)ks * OSZ;
#pragma unroll
    for (int mt = 0; mt < 4; ++mt)
#pragma unroll
      for (int rr = 0; rr < 4; ++rr) {
        int m = mt * 16 + q * 4 + rr;
        pb[(size_t)m * OUTN + orow] = facc[mt][rr];
      }
  } else {
#pragma unroll
    for (int mt = 0; mt < 4; ++mt)
#pragma unroll
      for (int rr = 0; rr < 4; ++rr) {
        int m = mt * 16 + q * 4 + rr;
        atomicAdd(&out[(size_t)m * OUTN + orow], facc[mt][rr]);
      }
  }
}

__global__ void qlin_reduce(const float* __restrict__ part, float* __restrict__ out) {
  const size_t i = ((size_t)blockIdx.x * 256 + threadIdx.x) * 4;
  float4 s = *(const float4*)(part + i);
#pragma unroll
  for (int ks = 1; ks < KSPLIT; ++ks) {
    float4 v = *(const float4*)(part + (size_t)ks * OSZ + i);
    s.x += v.x; s.y += v.y; s.z += v.z; s.w += v.w;
  }
  *(float4*)(out + i) = s;
}

extern "C" void kernel_launch(void* const* d_in, const int* in_sizes, int n_in,
                              void* d_out, int out_size, void* d_ws, size_t ws_size,
                              hipStream_t stream) {
  const float* x      = (const float*)d_in[0];
  const int*   packed = (const int*)d_in[1];
  const float* scales = (const float*)d_in[2];
  float* out = (float*)d_out;

  char* ws = (char*)d_ws;
  float*          xsum = (float*)ws;                     // 16 KB
  unsigned short* xswz = (unsigned short*)(ws + 16384);  // 1 MB
  const size_t part_need = 16384 + 1048576 + (size_t)KSPLIT * OSZ * sizeof(float);
  float* part = (ws_size >= part_need) ? (float*)(ws + 16384 + 1048576) : nullptr;

  qlin_prep<<<BATCHN, 256, 0, stream>>>(x, xsum);
  qlin_swz<<<(BATCHN * INN / 8) / 256, 256, 0, stream>>>(x, xswz);
  if (!part)
    hipMemsetAsync(d_out, 0, (size_t)out_size * sizeof(float), stream);
  qlin_main<<<(OUTN / BN) * KSPLIT, 256, 0, stream>>>(packed, scales, xswz, xsum, out, part);
  if (part)
    qlin_reduce<<<OSZ / 4 / 256, 256, 0, stream>>>(part, out);
}